// Round 4
// baseline (178.228 us; speedup 1.0000x reference)
//
#include <hip/hip_runtime.h>

typedef _Float16 half8 __attribute__((ext_vector_type(8)));
typedef _Float16 half4_t __attribute__((ext_vector_type(4)));
typedef float floatx4 __attribute__((ext_vector_type(4)));

#define H1P 136  // h1 scratch pitch in halves: 272B rows -> b64 writes 2-way (free), b128 reads conflict-free

// Prep: blocks [0,96) repack W1/W2 to MFMA A-frag order (fp16); block 96
// extracts W1[:,0]; blocks [97,..) convert x to fp16 (xh = L2-resident 6.4 MB).
__global__ __launch_bounds__(256) void prep_kernel(
    const float* __restrict__ x,
    const float* __restrict__ W1, const float* __restrict__ W2,
    _Float16* __restrict__ wsh, float* __restrict__ c0f,
    _Float16* __restrict__ xh, int n_x8)
{
    int b = blockIdx.x;
    if (b < 96) {
        int tid = b * 256 + threadIdx.x;
        if (tid < 16384) {                    // W1 cols 1..128: 8 mtiles x 4 kb x 512
            int c = tid >> 9, r = tid & 511;
            int L = r >> 3, jj = r & 7;
            int mt = c >> 2, kb = c & 3;
            int n = mt * 16 + (L & 15);
            int k = kb * 32 + (L >> 4) * 8 + jj;
            wsh[tid] = (_Float16)W1[n * 129 + 1 + k];
        } else {                              // W2: 4 mtiles x 4 kb x 512
            int t = tid - 16384;
            int c = t >> 9, r = t & 511;
            int L = r >> 3, jj = r & 7;
            int mt = c >> 2, kb = c & 3;
            int i = mt * 16 + (L & 15);
            int j = kb * 32 + (L >> 4) * 8 + jj;
            wsh[tid] = (_Float16)W2[i * 128 + j];
        }
    } else if (b == 96) {
        if (threadIdx.x < 128) c0f[threadIdx.x] = W1[threadIdx.x * 129];
    } else {
        int t2 = (b - 97) * 256 + threadIdx.x;
        if (t2 < n_x8) {
            const float4* p = (const float4*)(x + (size_t)t2 * 8);
            float4 v0 = p[0], v1 = p[1];
            half8 h = {(_Float16)v0.x, (_Float16)v0.y, (_Float16)v0.z, (_Float16)v0.w,
                       (_Float16)v1.x, (_Float16)v1.y, (_Float16)v1.z, (_Float16)v1.w};
            *(half8*)(xh + (size_t)t2 * 8) = h;
        }
    }
}

// Weight-resident waves: each wave holds all W1/W2 MFMA fragments + params in
// registers, strides over 16-edge tiles, gathers activations directly into
// B-fragment registers (no LDS staging), h1 round-trips through a wave-private
// 4 KB LDS scratch. No __syncthreads anywhere. 1 wave/SIMD by design.
__global__ __launch_bounds__(256, 1) void edge_mlp_kernel(
    const _Float16* __restrict__ xh,
    const int* __restrict__ ei,
    const float* __restrict__ ew,
    const float* __restrict__ b1, const float* __restrict__ c0f,
    const float* __restrict__ b2,
    const float* __restrict__ W3, const float* __restrict__ b3,
    const _Float16* __restrict__ wf,
    float* __restrict__ out, int E, int NT, int NW)
{
    __shared__ __align__(16) _Float16 h1s[4][16 * H1P];

    const int tid = threadIdx.x;
    const int lane = tid & 63;
    const int wave = tid >> 6;
    const int lrow = lane & 15;
    const int quad = lane >> 4;

    // ---- weights + params into registers (once per wave) ----
    half8 w1f[8][4], w2f[4][4];
#pragma unroll
    for (int mt = 0; mt < 8; ++mt)
#pragma unroll
        for (int kb = 0; kb < 4; ++kb)
            w1f[mt][kb] = *(const half8*)(wf + (mt * 4 + kb) * 512 + lane * 8);
#pragma unroll
    for (int mt = 0; mt < 4; ++mt)
#pragma unroll
        for (int kb = 0; kb < 4; ++kb)
            w2f[mt][kb] = *(const half8*)(wf + 16384 + (mt * 4 + kb) * 512 + lane * 8);

    floatx4 b1v[8], c0v[8], b2v[4], w3v[4];
#pragma unroll
    for (int mt = 0; mt < 8; ++mt) {
        b1v[mt] = *(const floatx4*)(b1 + mt * 16 + quad * 4);
        c0v[mt] = *(const floatx4*)(c0f + mt * 16 + quad * 4);
    }
#pragma unroll
    for (int mt = 0; mt < 4; ++mt) {
        b2v[mt] = *(const floatx4*)(b2 + mt * 16 + quad * 4);
        w3v[mt] = *(const floatx4*)(W3 + mt * 16 + quad * 4);
    }
    const float b3v = b3[0];

    _Float16* h1p = &h1s[wave][0];

    int t = blockIdx.x * 4 + wave;
    if (t >= NT) return;

    // ---- prefetch tile t into B-frag registers ----
    half8 cb[4]; float cew;
    {
        int e = t * 16 + lrow; if (e >= E) e = E - 1;
        int ns = ei[e], ntg = ei[E + e];
        const _Float16* ps = xh + (size_t)ns * 64;
        const _Float16* pt = xh + (size_t)ntg * 64;
        cb[0] = *(const half8*)(ps + quad * 8);
        cb[1] = *(const half8*)(ps + 32 + quad * 8);
        cb[2] = *(const half8*)(pt + quad * 8);
        cb[3] = *(const half8*)(pt + 32 + quad * 8);
        cew = ew[e];
    }

    while (t < NT) {
        const int tn = t + NW;
        // ---- issue next tile's gather early (hidden under this tile's MFMAs) ----
        half8 nb[4]; float new_;
        {
            int tt = (tn < NT) ? tn : t;
            int e2 = tt * 16 + lrow; if (e2 >= E) e2 = E - 1;
            int ns = ei[e2], ntg = ei[E + e2];
            const _Float16* ps = xh + (size_t)ns * 64;
            const _Float16* pt = xh + (size_t)ntg * 64;
            nb[0] = *(const half8*)(ps + quad * 8);
            nb[1] = *(const half8*)(ps + 32 + quad * 8);
            nb[2] = *(const half8*)(pt + quad * 8);
            nb[3] = *(const half8*)(pt + 32 + quad * 8);
            new_ = ew[e2];
        }

        // ---- layer 1: acc init = b1 + ew*W1[:,0]; 8 independent 4-MFMA chains ----
#pragma unroll
        for (int mt = 0; mt < 8; ++mt) {
            floatx4 a;
#pragma unroll
            for (int r = 0; r < 4; ++r)
                a[r] = b1v[mt][r] + cew * c0v[mt][r];
#pragma unroll
            for (int kb = 0; kb < 4; ++kb)
                a = __builtin_amdgcn_mfma_f32_16x16x32_f16(w1f[mt][kb], cb[kb], a, 0, 0, 0);
            half4_t hv;
#pragma unroll
            for (int r = 0; r < 4; ++r)
                hv[r] = (_Float16)fmaxf(a[r], 0.f);
            // C-layout -> wave-private LDS (in-order DS pipe; no barrier needed)
            *(half4_t*)(h1p + lrow * H1P + mt * 16 + quad * 4) = hv;
        }

        // ---- h1 back as B-fragments ----
        half8 hb[4];
#pragma unroll
        for (int kb = 0; kb < 4; ++kb)
            hb[kb] = *(const half8*)(h1p + lrow * H1P + kb * 32 + quad * 8);

        // ---- layer 2 (+fused layer 3 dot) ----
        float p = 0.f;
#pragma unroll
        for (int mt = 0; mt < 4; ++mt) {
            floatx4 a = b2v[mt];
#pragma unroll
            for (int kb = 0; kb < 4; ++kb)
                a = __builtin_amdgcn_mfma_f32_16x16x32_f16(w2f[mt][kb], hb[kb], a, 0, 0, 0);
#pragma unroll
            for (int r = 0; r < 4; ++r)
                p += fmaxf(a[r], 0.f) * w3v[mt][r];
        }
        p += __shfl_xor(p, 16, 64);
        p += __shfl_xor(p, 32, 64);
        int oe = t * 16 + lrow;
        if (quad == 0 && oe < E) out[oe] = p + b3v;

        t = tn;
        cb[0] = nb[0]; cb[1] = nb[1]; cb[2] = nb[2]; cb[3] = nb[3];
        cew = new_;
    }
}

extern "C" void kernel_launch(void* const* d_in, const int* in_sizes, int n_in,
                              void* d_out, int out_size, void* d_ws, size_t ws_size,
                              hipStream_t stream) {
    const float* x  = (const float*)d_in[0];
    const int*   ei = (const int*)d_in[1];   // int32 (verified round 1)
    const float* ew = (const float*)d_in[2];
    const float* W1 = (const float*)d_in[3];
    const float* b1 = (const float*)d_in[4];
    const float* W2 = (const float*)d_in[5];
    const float* b2 = (const float*)d_in[6];
    const float* W3 = (const float*)d_in[7];
    const float* b3 = (const float*)d_in[8];
    float* out = (float*)d_out;
    const int E = in_sizes[2];               // n_edges
    const int n_x = in_sizes[0];
    const int n_x8 = n_x / 8;

    _Float16* wsh = (_Float16*)d_ws;                   // 48 KiB frag-ordered weights
    float*    c0f = (float*)((char*)d_ws + 49152);     // W1[:,0], 512 B
    _Float16* xh  = (_Float16*)((char*)d_ws + 51200);  // fp16 x copy, 6.4 MB

    int xblk = (n_x8 + 255) / 256;
    prep_kernel<<<97 + xblk, 256, 0, stream>>>(x, W1, W2, wsh, c0f, xh, n_x8);

    const int NT = (E + 15) / 16;            // 16-edge tiles
    const int GRID = 512;                    // 2048 weight-resident waves
    const int NW = GRID * 4;
    edge_mlp_kernel<<<GRID, 256, 0, stream>>>(xh, ei, ew, b1, c0f, b2, W3, b3,
                                              wsh, out, E, NT, NW);
}

// Round 5
// 146.974 us; speedup vs baseline: 1.2126x; 1.2126x over previous
//
#include <hip/hip_runtime.h>

typedef _Float16 half8 __attribute__((ext_vector_type(8)));
typedef _Float16 half4_t __attribute__((ext_vector_type(4)));
typedef float floatx4 __attribute__((ext_vector_type(4)));

#define LP 136  // LDS row pitch in halves: 272B rows, 16B-aligned

// Prep: blocks [0,96) repack W1/W2 to MFMA A-frag order (fp16),
// blocks [96,..) convert x to fp16 (xh = 6.4 MB, mostly L2/L3-resident).
__global__ __launch_bounds__(256) void prep_kernel(
    const float* __restrict__ x,
    const float* __restrict__ W1, const float* __restrict__ W2,
    _Float16* __restrict__ wsh, _Float16* __restrict__ xh, int n_x8)
{
    int b = blockIdx.x;
    if (b < 96) {
        int tid = b * 256 + threadIdx.x;
        if (tid < 16384) {                    // W1 cols 1..128: 8 mtiles x 4 kb x 512
            int c = tid >> 9, r = tid & 511;
            int L = r >> 3, jj = r & 7;
            int mt = c >> 2, kb = c & 3;
            int n = mt * 16 + (L & 15);
            int k = kb * 32 + (L >> 4) * 8 + jj;
            wsh[tid] = (_Float16)W1[n * 129 + 1 + k];
        } else {                              // W2: 4 mtiles x 4 kb x 512
            int t = tid - 16384;
            int c = t >> 9, r = t & 511;
            int L = r >> 3, jj = r & 7;
            int mt = c >> 2, kb = c & 3;
            int i = mt * 16 + (L & 15);
            int j = kb * 32 + (L >> 4) * 8 + jj;
            wsh[tid] = (_Float16)W2[i * 128 + j];
        }
    } else {
        int t2 = (b - 96) * 256 + threadIdx.x;
        if (t2 < n_x8) {
            const float4* p = (const float4*)(x + (size_t)t2 * 8);
            float4 v0 = p[0], v1 = p[1];
            half8 h = {(_Float16)v0.x, (_Float16)v0.y, (_Float16)v0.z, (_Float16)v0.w,
                       (_Float16)v1.x, (_Float16)v1.y, (_Float16)v1.z, (_Float16)v1.w};
            *(half8*)(xh + (size_t)t2 * 8) = h;
        }
    }
}

// 2x2 hybrid split: wave (ns,es) computes output-quadrant [64 n x 64 e].
// B-frag LDS reads shared by only 2 waves; weights stream from global (L1-hot)
// hoisted per kb-step; accs held in registers across the alias barrier so h1
// reuses hA's LDS (block stays at ~37 KB).
__global__ __launch_bounds__(256, 4) void edge_mlp_kernel(
    const _Float16* __restrict__ xh,
    const int* __restrict__ ei,
    const float* __restrict__ ew,
    const float* __restrict__ W1, const float* __restrict__ b1,
    const float* __restrict__ b2,
    const float* __restrict__ W3, const float* __restrict__ b3,
    const _Float16* __restrict__ wf,
    float* __restrict__ out, int E)
{
    __shared__ __align__(16) _Float16 hA[128 * LP];  // features, then h1 (aliased)
    __shared__ float s_b1[128];
    __shared__ float s_c0[128];   // W1[:,0] (edge-weight column, rank-1 epilogue)
    __shared__ float s_b2[64];
    __shared__ float s_w3[64];
    __shared__ float s_out[2][128];

    const int tid = threadIdx.x;
    const int e_blk = blockIdx.x * 128;
    const int lane = tid & 63;
    const int wave = tid >> 6;
    const int ns = wave >> 1;     // n-half (0: outputs 0..63, 1: 64..127)
    const int es = wave & 1;      // e-half (0: edges 0..63, 1: 64..127)
    const int lrow = lane & 15;
    const int quad = lane >> 4;

    if (tid < 128) {
        s_b1[tid] = b1[tid];
        s_c0[tid] = W1[tid * 129];
    } else if (tid < 192) {
        int i = tid - 128;
        s_b2[i] = b2[i];
        s_w3[i] = W3[i];
    }

    // ---- gather fp16 node rows -> hA: k 0..63 = src, 64..127 = tgt ----
    {
        int e_loc = tid >> 1;
        int part = tid & 1;
        int e = e_blk + e_loc; if (e >= E) e = E - 1;
        int node = ei[(size_t)part * E + e];
        const _Float16* rp = xh + (size_t)node * 64;
        _Float16* dst = &hA[e_loc * LP + part * 64];
#pragma unroll
        for (int q = 0; q < 8; ++q)
            *(half8*)(dst + q * 8) = *(const half8*)(rp + q * 8);
    }

    float ewv[4];
#pragma unroll
    for (int et = 0; et < 4; ++et) {
        int e = e_blk + es * 64 + et * 16 + lrow;
        if (e >= E) e = E - 1;
        ewv[et] = ew[e];
    }
    __syncthreads();   // barrier 1: gather + params visible

    // ---- layer 1: acc[mt][et] over wave's quadrant, kb-outer ----
    floatx4 acc[4][4];
#pragma unroll
    for (int mt = 0; mt < 4; ++mt)
#pragma unroll
        for (int et = 0; et < 4; ++et)
            acc[mt][et] = (floatx4){0.f, 0.f, 0.f, 0.f};

#pragma unroll
    for (int kb = 0; kb < 4; ++kb) {
        half8 afr[4], bfr[4];
#pragma unroll
        for (int mt = 0; mt < 4; ++mt)
            afr[mt] = *(const half8*)(wf + (size_t)(((4 * ns + mt) * 4 + kb) * 512 + lane * 8));
#pragma unroll
        for (int et = 0; et < 4; ++et)
            bfr[et] = *(const half8*)(&hA[(es * 64 + et * 16 + lrow) * LP + kb * 32 + quad * 8]);
#pragma unroll
        for (int mt = 0; mt < 4; ++mt)
#pragma unroll
            for (int et = 0; et < 4; ++et)
                acc[mt][et] = __builtin_amdgcn_mfma_f32_16x16x32_f16(afr[mt], bfr[et], acc[mt][et], 0, 0, 0);
    }
    __syncthreads();   // barrier 2: all feature reads done -> safe to alias h1

    // ---- epilogue: bias + ew*c0, relu, write h1 (fp16) into hA as [e][n] ----
#pragma unroll
    for (int mt = 0; mt < 4; ++mt) {
        int nb = (4 * ns + mt) * 16 + quad * 4;
        floatx4 bb = *(const floatx4*)(&s_b1[nb]);
        floatx4 cc = *(const floatx4*)(&s_c0[nb]);
#pragma unroll
        for (int et = 0; et < 4; ++et) {
            half4_t hv;
#pragma unroll
            for (int r = 0; r < 4; ++r)
                hv[r] = (_Float16)fmaxf(acc[mt][et][r] + bb[r] + ewv[et] * cc[r], 0.f);
            *(half4_t*)(&hA[(es * 64 + et * 16 + lrow) * LP + nb]) = hv;
        }
    }
    __syncthreads();   // barrier 3: h1 complete (both ns halves)

    // ---- layer 2 (+fused layer 3): acc2[it][et], kb-outer ----
    floatx4 acc2[2][4];
#pragma unroll
    for (int it = 0; it < 2; ++it)
#pragma unroll
        for (int et = 0; et < 4; ++et)
            acc2[it][et] = (floatx4){0.f, 0.f, 0.f, 0.f};

#pragma unroll
    for (int kb = 0; kb < 4; ++kb) {
        half8 a2[2], hb[4];
#pragma unroll
        for (int it = 0; it < 2; ++it)
            a2[it] = *(const half8*)(wf + (size_t)(16384 + ((2 * ns + it) * 4 + kb) * 512 + lane * 8));
#pragma unroll
        for (int et = 0; et < 4; ++et)
            hb[et] = *(const half8*)(&hA[(es * 64 + et * 16 + lrow) * LP + kb * 32 + quad * 8]);
#pragma unroll
        for (int it = 0; it < 2; ++it)
#pragma unroll
            for (int et = 0; et < 4; ++et)
                acc2[it][et] = __builtin_amdgcn_mfma_f32_16x16x32_f16(a2[it], hb[et], acc2[it][et], 0, 0, 0);
    }

    float p[4] = {0.f, 0.f, 0.f, 0.f};
#pragma unroll
    for (int it = 0; it < 2; ++it) {
        int ib = (2 * ns + it) * 16 + quad * 4;
        floatx4 bb = *(const floatx4*)(&s_b2[ib]);
        floatx4 ww = *(const floatx4*)(&s_w3[ib]);
#pragma unroll
        for (int et = 0; et < 4; ++et)
#pragma unroll
            for (int r = 0; r < 4; ++r)
                p[et] += fmaxf(acc2[it][et][r] + bb[r], 0.f) * ww[r];
    }
#pragma unroll
    for (int et = 0; et < 4; ++et) {
        p[et] += __shfl_xor(p[et], 16, 64);
        p[et] += __shfl_xor(p[et], 32, 64);
    }
    if (quad == 0) {
#pragma unroll
        for (int et = 0; et < 4; ++et)
            s_out[ns][es * 64 + et * 16 + lrow] = p[et];
    }
    __syncthreads();   // barrier 4

    if (tid < 128) {
        int oe = e_blk + tid;
        if (oe < E)
            out[oe] = b3[0] + s_out[0][tid] + s_out[1][tid];
    }
}

extern "C" void kernel_launch(void* const* d_in, const int* in_sizes, int n_in,
                              void* d_out, int out_size, void* d_ws, size_t ws_size,
                              hipStream_t stream) {
    const float* x  = (const float*)d_in[0];
    const int*   ei = (const int*)d_in[1];   // int32 (verified round 1)
    const float* ew = (const float*)d_in[2];
    const float* W1 = (const float*)d_in[3];
    const float* b1 = (const float*)d_in[4];
    const float* W2 = (const float*)d_in[5];
    const float* b2 = (const float*)d_in[6];
    const float* W3 = (const float*)d_in[7];
    const float* b3 = (const float*)d_in[8];
    float* out = (float*)d_out;
    const int E = in_sizes[2];               // n_edges
    const int n_x = in_sizes[0];
    const int n_x8 = n_x / 8;

    _Float16* wsh = (_Float16*)d_ws;                  // 48 KiB frag-ordered weights
    _Float16* xh  = (_Float16*)((char*)d_ws + 49152); // fp16 x copy, 6.4 MB

    int xblk = (n_x8 + 255) / 256;
    prep_kernel<<<96 + xblk, 256, 0, stream>>>(x, W1, W2, wsh, xh, n_x8);

    int nblk = (E + 127) / 128;
    edge_mlp_kernel<<<nblk, 256, 0, stream>>>(xh, ei, ew, W1, b1, b2, W3, b3,
                                              wsh, out, E);
}